// Round 4
// baseline (206.501 us; speedup 1.0000x reference)
//
#include <hip/hip_runtime.h>
#include <stdint.h>

#define B 128
#define F 8192
#define H 8192
#define S 4
#define K 32
#define L 3
#define C 100

// ---------------------------------------------------------------------------
// Pack x (B,F) float {0,1} -> xT[f] = 128-bit mask over b (2 u64 words).
// Block = 128 threads (thread = b), each block handles 32 consecutive f
// (8 float4 loads / thread). Also zeroes d_out (fused, saves a launch).
// ---------------------------------------------------------------------------
__global__ void pack_x_kernel(const float* __restrict__ x, uint64_t* __restrict__ xT,
                              float* __restrict__ out) {
    const int zi = blockIdx.x * 128 + threadIdx.x;
    if (zi < B * C) out[zi] = 0.0f;

    const int b = threadIdx.x;           // 0..127
    const int f0 = blockIdx.x * 32;
    const float4* xr = (const float4*)(x + (size_t)b * F + f0);
    for (int j = 0; j < 8; ++j) {
        const float4 v = xr[j];
        const uint64_t m0 = __ballot(v.x > 0.5f);
        const uint64_t m1 = __ballot(v.y > 0.5f);
        const uint64_t m2 = __ballot(v.z > 0.5f);
        const uint64_t m3 = __ballot(v.w > 0.5f);
        if ((threadIdx.x & 63) == 0) {
            const int w = threadIdx.x >> 6;
            const int f = f0 + 4 * j;
            xT[(size_t)(f + 0) * 2 + w] = m0;
            xT[(size_t)(f + 1) * 2 + w] = m1;
            xT[(size_t)(f + 2) * 2 + w] = m2;
            xT[(size_t)(f + 3) * 2 + w] = m3;
        }
    }
}

__device__ __forceinline__ int load_threshold(const int* p) {
    // threshold is a tiny int; guard against the harness storing it as f32 bits
    int v = *p;
    if (v >= (1 << 23)) v = (int)__int_as_float(v);
    return v;
}

// ---------------------------------------------------------------------------
// One EISANI layer: prevT (Hprev x 128-bit) -> outT (H x 128-bit).
// One wave per TWO neurons (h0, h0+1); lane = batch (b=lane, b=lane+64).
// Staging: lanes 0..31 load idx, lanes 32..63 load signs (one per-lane VMEM
// load each), merged into packed = ik | neg<<16 via one shfl. The k-loop
// broadcast uses __shfl (DS, in-order lgkmcnt) and the column load stays a
// VMEM global_load_dwordx4 (in-order vmcnt) -> both pipeline under unroll 8.
// NO readfirstlane: SMEM retires out-of-order and forces lgkmcnt(0) serial.
// ---------------------------------------------------------------------------
__global__ void layer_kernel(const ulonglong2* __restrict__ prevT,
                             const int* __restrict__ idx,
                             const float* __restrict__ signs,
                             uint64_t* __restrict__ outT,
                             const int* __restrict__ thrp) {
    const int lane = threadIdx.x & 63;
    const int wv   = threadIdx.x >> 6;              // 0..3
    const int h0   = blockIdx.x * 8 + wv * 2;       // wave handles h0, h0+1
    const int thr  = load_threshold(thrp);
    const int l32  = lane & 31;

    bool fA0 = false, fA1 = false, fB0 = false, fB1 = false;
#pragma unroll
    for (int s = 0; s < S; ++s) {
        const int baseA = (s * H + h0) * K;
        const int baseB = baseA + K;
        // staged per-lane loads (VMEM, coalesced): idx on low half, signs on high
        int vA, vB;
        if (lane < 32) {
            vA = idx[baseA + l32];
            vB = idx[baseB + l32];
        } else {
            vA = __float_as_int(signs[baseA + l32]);
            vB = __float_as_int(signs[baseB + l32]);
        }
        const int sA = __shfl(vA, lane + 32, 64);   // sign word (valid lanes<32)
        const int sB = __shfl(vB, lane + 32, 64);
        const int pA = (vA & 0xFFFF) | ((((unsigned)sA) >> 31) << 16);
        const int pB = (vB & 0xFFFF) | ((((unsigned)sB) >> 31) << 16);

        int zA0 = 0, zA1 = 0, zB0 = 0, zB1 = 0;
#pragma unroll 8
        for (int k = 0; k < K; ++k) {
            const int a = __shfl(pA, k, 64);
            const int b = __shfl(pB, k, 64);
            const ulonglong2 colA = prevT[a & 0xFFFF];   // uniform 16B VMEM
            const ulonglong2 colB = prevT[b & 0xFFFF];
            const int svA = 1 - ((a >> 15) & 2);         // +1 / -1
            const int svB = 1 - ((b >> 15) & 2);
            zA0 += ((colA.x >> lane) & 1ull) ? svA : 0;
            zA1 += ((colA.y >> lane) & 1ull) ? svA : 0;
            zB0 += ((colB.x >> lane) & 1ull) ? svB : 0;
            zB1 += ((colB.y >> lane) & 1ull) ? svB : 0;
        }
        fA0 |= (zA0 >= thr);
        fA1 |= (zA1 >= thr);
        fB0 |= (zB0 >= thr);
        fB1 |= (zB1 >= thr);
    }
    const uint64_t mA0 = __ballot(fA0);
    const uint64_t mA1 = __ballot(fA1);
    const uint64_t mB0 = __ballot(fB0);
    const uint64_t mB1 = __ballot(fB1);
    if (lane == 0) {
        outT[(size_t)h0 * 2]     = mA0;
        outT[(size_t)h0 * 2 + 1] = mA1;
        outT[(size_t)h0 * 2 + 2] = mB0;
        outT[(size_t)h0 * 2 + 3] = mB1;
    }
}

// ---------------------------------------------------------------------------
// out[b][c] = sum_l sum_h act[l][b][h] * wout[l][h][c], act in {0,1}.
// Wave = one b; lanes = c (acc in 2 VGPRs: c=lane, c=lane+64).
// Grid = 32 b-groups x NHC h-chunks; block = 256 (4 waves = 4 consecutive b).
// Per 64-h round: coalesced mask load -> ballot -> set-bit walk with
// coalesced wout-row loads. Tail: <=2 atomics per lane.
// ---------------------------------------------------------------------------
#define NHC 16
#define HCH (H / NHC)   // 512 h per chunk

__global__ void final_kernel(const uint64_t* __restrict__ actT,
                             const float* __restrict__ wout,
                             float* __restrict__ out) {
    const int lane = threadIdx.x & 63;
    const int wid  = threadIdx.x >> 6;          // 0..3
    const int hc   = blockIdx.x & (NHC - 1);
    const int bg   = blockIdx.x / NHC;          // 0..31
    const int b    = bg * 4 + wid;              // wave-uniform
    const int word = b >> 6;                    // uniform within wave
    const int bit  = b & 63;

    float acc0 = 0.0f, acc1 = 0.0f;
    const int c1 = 64 + lane;
    const bool c1v = (c1 < C);

    for (int l = 0; l < L; ++l) {
        const uint64_t* aT = actT + (size_t)l * H * 2;
        const float* wl = wout + (size_t)l * H * C;
        for (int r = 0; r < HCH / 64; ++r) {
            const int hbase = hc * HCH + r * 64;
            const uint64_t m = aT[(size_t)(hbase + lane) * 2 + word];
            uint64_t hm = __ballot((m >> bit) & 1ull);
            while (hm) {
                const int slot = __ffsll((unsigned long long)hm) - 1;
                hm &= hm - 1;
                const float* wr = wl + (size_t)(hbase + slot) * C;
                acc0 += wr[lane];
                if (c1v) acc1 += wr[c1];
            }
        }
    }
    atomicAdd(&out[b * C + lane], acc0);
    if (c1v) atomicAdd(&out[b * C + c1], acc1);
}

// ---------------------------------------------------------------------------
extern "C" void kernel_launch(void* const* d_in, const int* in_sizes, int n_in,
                              void* d_out, int out_size, void* d_ws, size_t ws_size,
                              hipStream_t stream) {
    const float* x      = (const float*)d_in[0];   // (B,F)
    const float* signs0 = (const float*)d_in[1];   // (S,H,K)
    const float* signsH = (const float*)d_in[2];   // (L-1,S,H,K)
    const float* wout   = (const float*)d_in[3];   // (L,H,C)
    const int*   idx0   = (const int*)d_in[4];     // (S,H,K)
    const int*   idxH   = (const int*)d_in[5];     // (L-1,S,H,K)
    const int*   thr    = (const int*)d_in[6];     // scalar
    float* out = (float*)d_out;                    // (B,C)

    // Workspace: xT (F*2 u64) then actT (L*H*2 u64) -> 512 KiB total.
    uint64_t* xT   = (uint64_t*)d_ws;
    uint64_t* actT = xT + (size_t)F * 2;

    // pack x + zero out (fused)
    pack_x_kernel<<<F / 32, 128, 0, stream>>>(x, xT, out);

    // layer 0: from xT with idx0/signs0
    layer_kernel<<<H / 8, 256, 0, stream>>>((const ulonglong2*)xT, idx0, signs0,
                                            actT, thr);
    // layer 1: from actT[0] with idxH[0]/signsH[0]
    layer_kernel<<<H / 8, 256, 0, stream>>>((const ulonglong2*)actT,
                                            idxH, signsH,
                                            actT + (size_t)H * 2, thr);
    // layer 2: from actT[1] with idxH[1]/signsH[1]
    layer_kernel<<<H / 8, 256, 0, stream>>>((const ulonglong2*)(actT + (size_t)H * 2),
                                            idxH + (size_t)S * H * K,
                                            signsH + (size_t)S * H * K,
                                            actT + (size_t)2 * H * 2, thr);

    final_kernel<<<32 * NHC, 256, 0, stream>>>(actT, wout, out);
}

// Round 5
// 176.272 us; speedup vs baseline: 1.1715x; 1.1715x over previous
//
#include <hip/hip_runtime.h>
#include <stdint.h>

#define B 128
#define F 8192
#define H 8192
#define S 4
#define K 32
#define L 3
#define C 100

// ---------------------------------------------------------------------------
// Pack x (B,F) float {0,1} -> xT[f] = 128-bit mask over b (2 u64 words).
// Block = 128 threads (thread = b), each block handles 32 consecutive f
// (8 float4 loads / thread). Also zeroes d_out (fused, saves a launch).
// ---------------------------------------------------------------------------
__global__ void pack_x_kernel(const float* __restrict__ x, uint64_t* __restrict__ xT,
                              float* __restrict__ out) {
    const int zi = blockIdx.x * 128 + threadIdx.x;
    if (zi < B * C) out[zi] = 0.0f;

    const int b = threadIdx.x;           // 0..127
    const int f0 = blockIdx.x * 32;
    const float4* xr = (const float4*)(x + (size_t)b * F + f0);
    for (int j = 0; j < 8; ++j) {
        const float4 v = xr[j];
        const uint64_t m0 = __ballot(v.x > 0.5f);
        const uint64_t m1 = __ballot(v.y > 0.5f);
        const uint64_t m2 = __ballot(v.z > 0.5f);
        const uint64_t m3 = __ballot(v.w > 0.5f);
        if ((threadIdx.x & 63) == 0) {
            const int w = threadIdx.x >> 6;
            const int f = f0 + 4 * j;
            xT[(size_t)(f + 0) * 2 + w] = m0;
            xT[(size_t)(f + 1) * 2 + w] = m1;
            xT[(size_t)(f + 2) * 2 + w] = m2;
            xT[(size_t)(f + 3) * 2 + w] = m3;
        }
    }
}

__device__ __forceinline__ int load_threshold(const int* p) {
    // threshold is a tiny int; guard against the harness storing it as f32 bits
    int v = *p;
    if (v >= (1 << 23)) v = (int)__int_as_float(v);
    return v;
}

// ---------------------------------------------------------------------------
// One EISANI layer: prevT (Hprev x 128-bit) -> outT (H x 128-bit).
// One wave per neuron h; lane = batch (b=lane and b=lane+64).
// All 4 segments' idx/signs staged upfront (coalesced VMEM, one latency hit).
// k-loop: 8 wave-uniform indices extracted via readlane (compile-time lanes),
// 8 uniform column loads issued back-to-back (scalar-load pipelining, one
// waitcnt per chunk), then consumed with z += bit*sv (v_mad_i32_i24 path:
// ~6 VALU per column for both 64-batch words).
// ---------------------------------------------------------------------------
__global__ void layer_kernel(const ulonglong2* __restrict__ prevT,
                             const int* __restrict__ idx,
                             const float* __restrict__ signs,
                             uint64_t* __restrict__ outT,
                             const int* __restrict__ thrp) {
    const int lane = threadIdx.x & 63;
    const int h = blockIdx.x * 4 + (threadIdx.x >> 6);
    const int thr = load_threshold(thrp);

    // stage all segments upfront: packed = ik | (neg<<16), valid on lanes<32
    int pk[S];
#pragma unroll
    for (int s = 0; s < S; ++s) {
        pk[s] = 0;
        if (lane < K) {
            const int off = (s * H + h) * K + lane;
            const int neg = (signs[off] < 0.0f) ? 1 : 0;
            pk[s] = idx[off] | (neg << 16);
        }
    }

    bool f0 = false, f1 = false;
#pragma unroll
    for (int s = 0; s < S; ++s) {
        int z0 = 0, z1 = 0;
#pragma unroll
        for (int kc = 0; kc < K; kc += 8) {
            int p[8];
#pragma unroll
            for (int j = 0; j < 8; ++j)
                p[j] = __builtin_amdgcn_readlane(pk[s], kc + j);   // uniform
            ulonglong2 c[8];
#pragma unroll
            for (int j = 0; j < 8; ++j)
                c[j] = prevT[p[j] & 0xFFFF];                        // 8 in flight
#pragma unroll
            for (int j = 0; j < 8; ++j) {
                const int sv = 1 - ((p[j] >> 15) & 2);              // +1 / -1
                const int b0 = (int)((c[j].x >> lane) & 1ull);
                const int b1 = (int)((c[j].y >> lane) & 1ull);
                z0 += b0 * sv;
                z1 += b1 * sv;
            }
        }
        f0 |= (z0 >= thr);
        f1 |= (z1 >= thr);
    }
    const uint64_t m0 = __ballot(f0);
    const uint64_t m1 = __ballot(f1);
    if (lane == 0) {
        ulonglong2* o = (ulonglong2*)outT;
        o[h] = make_ulonglong2(m0, m1);
    }
}

// ---------------------------------------------------------------------------
// out[b][c] = sum_l sum_h act[l][b][h] * wout[l][h][c], act in {0,1}.
// Wave = one b; lanes = c (acc in 2 VGPRs: c=lane, c=lane+64).
// Grid = 32 b-groups x NHC h-chunks; block = 256 (4 waves = 4 consecutive b).
// Per 64-h round: coalesced mask load -> ballot -> set-bit walk with
// coalesced wout-row loads. Tail: <=2 atomics per lane.
// ---------------------------------------------------------------------------
#define NHC 16
#define HCH (H / NHC)   // 512 h per chunk

__global__ void final_kernel(const uint64_t* __restrict__ actT,
                             const float* __restrict__ wout,
                             float* __restrict__ out) {
    const int lane = threadIdx.x & 63;
    const int wid  = threadIdx.x >> 6;          // 0..3
    const int hc   = blockIdx.x & (NHC - 1);
    const int bg   = blockIdx.x / NHC;          // 0..31
    const int b    = bg * 4 + wid;              // wave-uniform
    const int word = b >> 6;                    // uniform within wave
    const int bit  = b & 63;

    float acc0 = 0.0f, acc1 = 0.0f;
    const int c1 = 64 + lane;
    const bool c1v = (c1 < C);

    for (int l = 0; l < L; ++l) {
        const uint64_t* aT = actT + (size_t)l * H * 2;
        const float* wl = wout + (size_t)l * H * C;
        for (int r = 0; r < HCH / 64; ++r) {
            const int hbase = hc * HCH + r * 64;
            const uint64_t m = aT[(size_t)(hbase + lane) * 2 + word];
            uint64_t hm = __ballot((m >> bit) & 1ull);
            while (hm) {
                const int slot = __ffsll((unsigned long long)hm) - 1;
                hm &= hm - 1;
                const float* wr = wl + (size_t)(hbase + slot) * C;
                acc0 += wr[lane];
                if (c1v) acc1 += wr[c1];
            }
        }
    }
    atomicAdd(&out[b * C + lane], acc0);
    if (c1v) atomicAdd(&out[b * C + c1], acc1);
}

// ---------------------------------------------------------------------------
extern "C" void kernel_launch(void* const* d_in, const int* in_sizes, int n_in,
                              void* d_out, int out_size, void* d_ws, size_t ws_size,
                              hipStream_t stream) {
    const float* x      = (const float*)d_in[0];   // (B,F)
    const float* signs0 = (const float*)d_in[1];   // (S,H,K)
    const float* signsH = (const float*)d_in[2];   // (L-1,S,H,K)
    const float* wout   = (const float*)d_in[3];   // (L,H,C)
    const int*   idx0   = (const int*)d_in[4];     // (S,H,K)
    const int*   idxH   = (const int*)d_in[5];     // (L-1,S,H,K)
    const int*   thr    = (const int*)d_in[6];     // scalar
    float* out = (float*)d_out;                    // (B,C)

    // Workspace: xT (F*2 u64) then actT (L*H*2 u64) -> 512 KiB total.
    uint64_t* xT   = (uint64_t*)d_ws;
    uint64_t* actT = xT + (size_t)F * 2;

    // pack x + zero out (fused)
    pack_x_kernel<<<F / 32, 128, 0, stream>>>(x, xT, out);

    // layer 0: from xT with idx0/signs0
    layer_kernel<<<H / 4, 256, 0, stream>>>((const ulonglong2*)xT, idx0, signs0,
                                            actT, thr);
    // layer 1: from actT[0] with idxH[0]/signsH[0]
    layer_kernel<<<H / 4, 256, 0, stream>>>((const ulonglong2*)actT,
                                            idxH, signsH,
                                            actT + (size_t)H * 2, thr);
    // layer 2: from actT[1] with idxH[1]/signsH[1]
    layer_kernel<<<H / 4, 256, 0, stream>>>((const ulonglong2*)(actT + (size_t)H * 2),
                                            idxH + (size_t)S * H * K,
                                            signsH + (size_t)S * H * K,
                                            actT + (size_t)2 * H * 2, thr);

    final_kernel<<<32 * NHC, 256, 0, stream>>>(actT, wout, out);
}

// Round 6
// 129.139 us; speedup vs baseline: 1.5991x; 1.3650x over previous
//
#include <hip/hip_runtime.h>
#include <stdint.h>

#define B 128
#define F 8192
#define H 8192
#define S 4
#define K 32
#define L 3
#define C 100

// ---------------------------------------------------------------------------
// Pack x (B,F) float {0,1} -> PLANAR bit tables xP[w][f], w = b-word (b>>6),
// bit position = b & 63. Block = 128 threads (thread = b), 32 f per block.
// Also zeroes d_out (fused, saves a launch).
// ---------------------------------------------------------------------------
__global__ void pack_x_kernel(const float* __restrict__ x, uint64_t* __restrict__ xP,
                              float* __restrict__ out) {
    const int zi = blockIdx.x * 128 + threadIdx.x;
    if (zi < B * C) out[zi] = 0.0f;

    const int b = threadIdx.x;           // 0..127
    const int w = threadIdx.x >> 6;      // b-word
    const int f0 = blockIdx.x * 32;
    const float4* xr = (const float4*)(x + (size_t)b * F + f0);
    for (int j = 0; j < 8; ++j) {
        const float4 v = xr[j];
        const uint64_t m0 = __ballot(v.x > 0.5f);
        const uint64_t m1 = __ballot(v.y > 0.5f);
        const uint64_t m2 = __ballot(v.z > 0.5f);
        const uint64_t m3 = __ballot(v.w > 0.5f);
        if ((threadIdx.x & 63) == 0) {
            const int f = f0 + 4 * j;
            xP[(size_t)w * F + f + 0] = m0;
            xP[(size_t)w * F + f + 1] = m1;
            xP[(size_t)w * F + f + 2] = m2;
            xP[(size_t)w * F + f + 3] = m3;
        }
    }
}

__device__ __forceinline__ int load_threshold(const int* p) {
    // threshold is a tiny int; guard against the harness storing it as f32 bits
    int v = *p;
    if (v >= (1 << 23)) v = (int)__int_as_float(v);
    return v;
}

// ---------------------------------------------------------------------------
// BIT-SLICED layer: prevP[w][hprev] (planar u64 masks) -> outP[w][h].
// lane = neuron h (64 h per block); the 64-batch mask word is per-lane DATA.
// Block = 256 = 4 waves; wave = one segment s. blockIdx: bit0 = word w,
// rest = h-group. Per k: LDS gather of the column word + sign mask +
// two carry-save bit-sliced counter adds (A = sum a, P = sum a&pos).
// fired = (2P >= A + thr) evaluated bit-sliced; OR across segments via LDS.
// One instruction serves 64 h x 64 b.
// ---------------------------------------------------------------------------
__global__ void layer_kernel(const uint64_t* __restrict__ prevP,
                             const int* __restrict__ idx,
                             const float* __restrict__ signs,
                             uint64_t* __restrict__ outP,
                             const int* __restrict__ thrp) {
    __shared__ uint64_t tab[H];                       // 64 KiB
    const int tid  = threadIdx.x;
    const int lane = tid & 63;
    const int s    = tid >> 6;                        // wave = segment
    const int w    = blockIdx.x & 1;
    const int hg   = blockIdx.x >> 1;
    const int h    = hg * 64 + lane;
    const int thr  = load_threshold(thrp);

    // stage the word-w table (coalesced 16B loads, 16 iters over 4 waves)
    {
        const ulonglong2* src = (const ulonglong2*)(prevP + (size_t)w * H);
        ulonglong2* dst = (ulonglong2*)tab;
#pragma unroll
        for (int i = 0; i < 16; ++i)
            dst[i * 256 + tid] = src[i * 256 + tid];
    }
    __syncthreads();

    uint64_t A[6] = {0, 0, 0, 0, 0, 0};               // sum of a      (<=32)
    uint64_t P[6] = {0, 0, 0, 0, 0, 0};               // sum of a&pos  (<=32)
    const int4*   irow = (const int4*)(idx   + ((size_t)s * H + h) * K);
    const float4* srow = (const float4*)(signs + ((size_t)s * H + h) * K);
#pragma unroll
    for (int kk = 0; kk < 8; ++kk) {
        const int4   i4 = irow[kk];
        const float4 s4 = srow[kk];
        const int   iv[4] = {i4.x, i4.y, i4.z, i4.w};
        const float sv[4] = {s4.x, s4.y, s4.z, s4.w};
#pragma unroll
        for (int j = 0; j < 4; ++j) {
            const uint64_t a  = tab[iv[j]];           // per-lane LDS gather
            // posmask = ~0 if sign >= 0 else 0 (from the float's sign bit)
            const uint64_t pm = (uint64_t)(int64_t)(~(__float_as_int(sv[j]) >> 31));
            uint64_t c = a;                           // A += a (carry-save)
#pragma unroll
            for (int i = 0; i < 6; ++i) { const uint64_t t = A[i]; A[i] = t ^ c; c = t & c; }
            c = a & pm;                               // P += a & pos
#pragma unroll
            for (int i = 0; i < 6; ++i) { const uint64_t t = P[i]; P[i] = t ^ c; c = t & c; }
        }
    }

    // fired = (2P >= A + thr), 7-bit bit-sliced unsigned compare.
    // Y = A + thr (thr wave-uniform; full-adder with broadcast constant bit).
    uint64_t Y[7];
    {
        uint64_t c = 0;
#pragma unroll
        for (int i = 0; i < 7; ++i) {
            const uint64_t ai = (i < 6) ? A[i] : 0ull;
            const uint64_t bm = ((thr >> i) & 1) ? ~0ull : 0ull;
            const uint64_t t  = ai ^ bm;
            Y[i] = t ^ c;
            c = (ai & bm) | (t & c);
        }
    }
    // X = 2P (planes shifted up by one); X >= Y  <=>  no borrow in X - Y.
    uint64_t bw = 0;
#pragma unroll
    for (int i = 0; i < 7; ++i) {
        const uint64_t x = (i >= 1) ? P[i - 1] : 0ull;
        const uint64_t d = x ^ Y[i];
        bw = ((~x) & Y[i]) | ((~d) & bw);
    }
    const uint64_t fired = ~bw;

    // OR across the 4 segment-waves (reuse tab region after a barrier).
    __syncthreads();                                  // all tab reads done
    uint64_t* fsbuf = tab;
    fsbuf[s * 64 + lane] = fired;
    __syncthreads();
    if (s == 0) {
        const uint64_t f = fsbuf[lane] | fsbuf[64 + lane] |
                           fsbuf[128 + lane] | fsbuf[192 + lane];
        outP[(size_t)w * H + h] = f;                  // coalesced 8B stores
    }
}

// ---------------------------------------------------------------------------
// out[b][c] = sum_l sum_h act[l][b][h] * wout[l][h][c], act in {0,1}.
// Wave = one b; lanes = c (acc in 2 VGPRs: c=lane, c=lane+64).
// Grid = 32 b-groups x NHC h-chunks; block = 256 (4 waves = 4 consecutive b).
// Planar masks: actP[(l*2+word)*H + h].
// ---------------------------------------------------------------------------
#define NHC 16
#define HCH (H / NHC)   // 512 h per chunk

__global__ void final_kernel(const uint64_t* __restrict__ actP,
                             const float* __restrict__ wout,
                             float* __restrict__ out) {
    const int lane = threadIdx.x & 63;
    const int wid  = threadIdx.x >> 6;          // 0..3
    const int hc   = blockIdx.x & (NHC - 1);
    const int bg   = blockIdx.x / NHC;          // 0..31
    const int b    = bg * 4 + wid;              // wave-uniform
    const int word = b >> 6;                    // uniform within wave
    const int bit  = b & 63;

    float acc0 = 0.0f, acc1 = 0.0f;
    const int c1 = 64 + lane;
    const bool c1v = (c1 < C);

    for (int l = 0; l < L; ++l) {
        const uint64_t* aT = actP + ((size_t)l * 2 + word) * H;
        const float* wl = wout + (size_t)l * H * C;
        for (int r = 0; r < HCH / 64; ++r) {
            const int hbase = hc * HCH + r * 64;
            const uint64_t m = aT[hbase + lane];
            uint64_t hm = __ballot((m >> bit) & 1ull);
            while (hm) {
                const int slot = __ffsll((unsigned long long)hm) - 1;
                hm &= hm - 1;
                const float* wr = wl + (size_t)(hbase + slot) * C;
                acc0 += wr[lane];
                if (c1v) acc1 += wr[c1];
            }
        }
    }
    atomicAdd(&out[b * C + lane], acc0);
    if (c1v) atomicAdd(&out[b * C + c1], acc1);
}

// ---------------------------------------------------------------------------
extern "C" void kernel_launch(void* const* d_in, const int* in_sizes, int n_in,
                              void* d_out, int out_size, void* d_ws, size_t ws_size,
                              hipStream_t stream) {
    const float* x      = (const float*)d_in[0];   // (B,F)
    const float* signs0 = (const float*)d_in[1];   // (S,H,K)
    const float* signsH = (const float*)d_in[2];   // (L-1,S,H,K)
    const float* wout   = (const float*)d_in[3];   // (L,H,C)
    const int*   idx0   = (const int*)d_in[4];     // (S,H,K)
    const int*   idxH   = (const int*)d_in[5];     // (L-1,S,H,K)
    const int*   thr    = (const int*)d_in[6];     // scalar
    float* out = (float*)d_out;                    // (B,C)

    // Workspace (planar): xP [2][F] u64 (128 KiB), actP [L][2][H] u64 (384 KiB)
    uint64_t* xP   = (uint64_t*)d_ws;
    uint64_t* actP = xP + (size_t)2 * F;

    // pack x + zero out (fused)
    pack_x_kernel<<<F / 32, 128, 0, stream>>>(x, xP, out);

    // layer 0: from xP with idx0/signs0
    layer_kernel<<<256, 256, 0, stream>>>(xP, idx0, signs0, actP, thr);
    // layer 1: from actP[0] with idxH[0]/signsH[0]
    layer_kernel<<<256, 256, 0, stream>>>(actP, idxH, signsH,
                                          actP + (size_t)2 * H, thr);
    // layer 2: from actP[1] with idxH[1]/signsH[1]
    layer_kernel<<<256, 256, 0, stream>>>(actP + (size_t)2 * H,
                                          idxH + (size_t)S * H * K,
                                          signsH + (size_t)S * H * K,
                                          actP + (size_t)4 * H, thr);

    final_kernel<<<32 * NHC, 256, 0, stream>>>(actP, wout, out);
}